// Round 10
// baseline (612.826 us; speedup 1.0000x reference)
//
#include <hip/hip_runtime.h>
#include <math.h>

#define N_OBS_C 2000000
#define N_REFL_C 250000
#define N_IMG_C 2000
#define MC_C 32
#define HID 64
#define NSLOT 16
#define REP 4
#define LOG2PI_F 1.8378770664093453f

// ---------------- workspace layout (bytes) ----------------
// [0,64)        accs: 8 doubles (kl, llmax, W, Sx, Sy, Sxx, Syy, Sxy)
// [64,1536064)  img_mom [2000][12][NSLOT] float  (zeroed by k_zero)
// [2097152,..)  sq [250000] float
// [4194304,..)  img_pre [2000][64] float
// [8388608,..)  zT [250000][32] float (32MB)
// [50331648,..) params [2000000] float4 (32MB)
//
// NOTE: k_mlp / k_mc run their body REP=4 times with an opaque 0 offset
// (measurement instrumentation so they surface in rocprof top-5).

__device__ __forceinline__ float softplusf(float x) {
    return (x > 20.f) ? x : log1pf(expf(x));
}

// ---- K0: zero the accumulator region ----
#define ZERO_F4 96004   // (64 + 2000*12*16*4) / 16
__global__ __launch_bounds__(256) void k_zero(float4* __restrict__ p) {
    int i = blockIdx.x * 256 + threadIdx.x;
    if (i < ZERO_F4) p[i] = make_float4(0.f, 0.f, 0.f, 0.f);
}

// ---- K1: per-reflection: sq, KL partial, zT table ----
__global__ __launch_bounds__(256) void k_refl(const float* __restrict__ q_loc,
                                              const float* __restrict__ q_scale_raw,
                                              const float* __restrict__ zeps,
                                              float* __restrict__ sq,
                                              float* __restrict__ zT,
                                              double* __restrict__ kl_sum) {
    int r = blockIdx.x * 256 + threadIdx.x;
    double kl = 0.0;
    if (r < N_REFL_C) {
        float ql = q_loc[r];
        float sp = softplusf(q_scale_raw[r]);
        sq[r] = sp;
        kl = (double)(-logf(sp) + 0.5f * (sp * sp + ql * ql) - 0.5f);
        float z[MC_C];
#pragma unroll
        for (int m = 0; m < MC_C; ++m)
            z[m] = fmaf(sp, zeps[(size_t)m * N_REFL_C + r], ql);
        float4* outp = (float4*)(zT + (size_t)r * MC_C);
#pragma unroll
        for (int q = 0; q < MC_C / 4; ++q)
            outp[q] = make_float4(z[4 * q], z[4 * q + 1], z[4 * q + 2], z[4 * q + 3]);
    }
    for (int o = 32; o > 0; o >>= 1) kl += __shfl_xor(kl, o);
    __shared__ double skl[4];
    int lane = threadIdx.x & 63, w = threadIdx.x >> 6;
    if (lane == 0) skl[w] = kl;
    __syncthreads();
    if (threadIdx.x == 0) atomicAdd(kl_sum, skl[0] + skl[1] + skl[2] + skl[3]);
}

// ---- K1b: per-image precompute ----
__global__ __launch_bounds__(64) void k_imgpre(const float* __restrict__ img_emb,
                                               const float* __restrict__ W1,
                                               const float* __restrict__ b1,
                                               float* __restrict__ img_pre) {
    int g = blockIdx.x;
    int j = threadIdx.x;
    float acc = b1[j];
#pragma unroll
    for (int e = 0; e < 32; ++e)
        acc = fmaf(img_emb[g * 32 + e], W1[(12 + e) * HID + j], acc);
    img_pre[g * HID + j] = acc;
}

// ---- K2a: MLP, 2 obs per thread; weights in LDS; REP-instrumented ----
__global__ __launch_bounds__(256) void k_mlp(const float* __restrict__ I,
                                             const float* __restrict__ SigI,
                                             const int* __restrict__ image_id,
                                             const float* __restrict__ metadata,
                                             const float* __restrict__ wavelength,
                                             const float* __restrict__ dHKL,
                                             const int* __restrict__ refl_ids,
                                             const float* __restrict__ q_loc,
                                             const float* __restrict__ W1,
                                             const float* __restrict__ W2,
                                             const float* __restrict__ b2,
                                             const float* __restrict__ sq,
                                             const float* __restrict__ img_pre,
                                             float4* __restrict__ params,
                                             int opaq) {
    __shared__ float sW1[12 * HID];
    __shared__ float sW2a[HID], sW2b[HID];
    for (int t = threadIdx.x; t < 12 * HID; t += 256) sW1[t] = W1[t];
    if (threadIdx.x < HID) {
        sW2a[threadIdx.x] = W2[threadIdx.x * 2 + 0];
        sW2b[threadIdx.x] = W2[threadIdx.x * 2 + 1];
    }
    __syncthreads();

    for (int r = 0; r < REP; ++r) {
        int base = r * opaq;   // 0 at runtime; opaque to compiler
        int n0 = blockIdx.x * 512 + threadIdx.x + base;
        int n1 = n0 + 256;
        bool a0 = (n0 < N_OBS_C), a1 = (n1 < N_OBS_C);
        int m0 = a0 ? n0 : (N_OBS_C - 1);
        int m1 = a1 ? n1 : (N_OBS_C - 1);

        float f0[12], f1[12];
        f0[2] = I[m0];   f1[2] = I[m1];
        f0[3] = SigI[m0]; f1[3] = SigI[m1];
#pragma unroll
        for (int i = 0; i < 6; ++i) {
            f0[4 + i] = metadata[(size_t)m0 * 6 + i];
            f1[4 + i] = metadata[(size_t)m1 * 6 + i];
        }
        f0[10] = wavelength[m0]; f1[10] = wavelength[m1];
        float dh0 = dHKL[m0], dh1 = dHKL[m1];
        f0[11] = 1.0f / (dh0 * dh0);
        f1[11] = 1.0f / (dh1 * dh1);
        int g0 = image_id[m0], g1 = image_id[m1];
        int r00 = refl_ids[m0], r01 = refl_ids[N_OBS_C + m0];
        int r10 = refl_ids[m1], r11 = refl_ids[N_OBS_C + m1];
        float qa0 = q_loc[r00], sa0 = sq[r00];
        float qb0 = q_loc[r01], sb0 = sq[r01];
        float qa1 = q_loc[r10], sa1 = sq[r10];
        float qb1 = q_loc[r11], sb1 = sq[r11];
        const float* ip0 = img_pre + (size_t)g0 * HID;
        const float* ip1 = img_pre + (size_t)g1 * HID;

        float bb0 = b2[0], bb1 = b2[1];
        float la00 = bb0, la01 = bb1, lb00 = bb0, lb01 = bb1;
        float la10 = bb0, la11 = bb1, lb10 = bb0, lb11 = bb1;

#pragma unroll 1
        for (int jt = 0; jt < HID; jt += 8) {
            int jo = jt + base;   // opaque: forces DS re-issue across reps
            float acc0[8], acc1[8];
            {
                float4 p0a = *(const float4*)&ip0[jo];
                float4 p0b = *(const float4*)&ip0[jo + 4];
                float4 p1a = *(const float4*)&ip1[jo];
                float4 p1b = *(const float4*)&ip1[jo + 4];
                acc0[0] = p0a.x; acc0[1] = p0a.y; acc0[2] = p0a.z; acc0[3] = p0a.w;
                acc0[4] = p0b.x; acc0[5] = p0b.y; acc0[6] = p0b.z; acc0[7] = p0b.w;
                acc1[0] = p1a.x; acc1[1] = p1a.y; acc1[2] = p1a.z; acc1[3] = p1a.w;
                acc1[4] = p1b.x; acc1[5] = p1b.y; acc1[6] = p1b.z; acc1[7] = p1b.w;
            }
#pragma unroll
            for (int i = 2; i < 12; ++i) {
                float4 wa = *(const float4*)&sW1[i * HID + jo];
                float4 wb = *(const float4*)&sW1[i * HID + jo + 4];
                float u0 = f0[i], u1 = f1[i];
                acc0[0] = fmaf(u0, wa.x, acc0[0]); acc1[0] = fmaf(u1, wa.x, acc1[0]);
                acc0[1] = fmaf(u0, wa.y, acc0[1]); acc1[1] = fmaf(u1, wa.y, acc1[1]);
                acc0[2] = fmaf(u0, wa.z, acc0[2]); acc1[2] = fmaf(u1, wa.z, acc1[2]);
                acc0[3] = fmaf(u0, wa.w, acc0[3]); acc1[3] = fmaf(u1, wa.w, acc1[3]);
                acc0[4] = fmaf(u0, wb.x, acc0[4]); acc1[4] = fmaf(u1, wb.x, acc1[4]);
                acc0[5] = fmaf(u0, wb.y, acc0[5]); acc1[5] = fmaf(u1, wb.y, acc1[5]);
                acc0[6] = fmaf(u0, wb.z, acc0[6]); acc1[6] = fmaf(u1, wb.z, acc1[6]);
                acc0[7] = fmaf(u0, wb.w, acc0[7]); acc1[7] = fmaf(u1, wb.w, acc1[7]);
            }
            float4 w0a = *(const float4*)&sW1[jo];
            float4 w0b = *(const float4*)&sW1[jo + 4];
            float4 w1a = *(const float4*)&sW1[HID + jo];
            float4 w1b = *(const float4*)&sW1[HID + jo + 4];
            float w0r[8] = {w0a.x, w0a.y, w0a.z, w0a.w, w0b.x, w0b.y, w0b.z, w0b.w};
            float w1r[8] = {w1a.x, w1a.y, w1a.z, w1a.w, w1b.x, w1b.y, w1b.z, w1b.w};
            float4 va4a = *(const float4*)&sW2a[jo];
            float4 va4b = *(const float4*)&sW2a[jo + 4];
            float4 vb4a = *(const float4*)&sW2b[jo];
            float4 vb4b = *(const float4*)&sW2b[jo + 4];
            float va[8] = {va4a.x, va4a.y, va4a.z, va4a.w, va4b.x, va4b.y, va4b.z, va4b.w};
            float vb[8] = {vb4a.x, vb4a.y, vb4a.z, vb4a.w, vb4b.x, vb4b.y, vb4b.z, vb4b.w};
#pragma unroll
            for (int jj = 0; jj < 8; ++jj) {
                float ha0 = fmaxf(fmaf(qa0, w0r[jj], fmaf(sa0, w1r[jj], acc0[jj])), 0.f);
                la00 = fmaf(ha0, va[jj], la00);
                la01 = fmaf(ha0, vb[jj], la01);
                float hb0 = fmaxf(fmaf(qb0, w0r[jj], fmaf(sb0, w1r[jj], acc0[jj])), 0.f);
                lb00 = fmaf(hb0, va[jj], lb00);
                lb01 = fmaf(hb0, vb[jj], lb01);
                float ha1 = fmaxf(fmaf(qa1, w0r[jj], fmaf(sa1, w1r[jj], acc1[jj])), 0.f);
                la10 = fmaf(ha1, va[jj], la10);
                la11 = fmaf(ha1, vb[jj], la11);
                float hb1 = fmaxf(fmaf(qb1, w0r[jj], fmaf(sb1, w1r[jj], acc1[jj])), 0.f);
                lb10 = fmaf(hb1, va[jj], lb10);
                lb11 = fmaf(hb1, vb[jj], lb11);
            }
        }

        if (a0) params[n0] = make_float4(la00, softplusf(la01), lb00, softplusf(lb01));
        if (a1) params[n1] = make_float4(la10, softplusf(la11), lb10, softplusf(lb11));
    }
}

// ---- K2b: MC likelihood + fused moments; 8 lanes/obs; REP-instrumented ----
__global__ __launch_bounds__(256) void k_mc(const float* __restrict__ I,
                                            const float* __restrict__ SigI,
                                            const int* __restrict__ image_id,
                                            const int* __restrict__ refl_ids,
                                            const float4* __restrict__ params,
                                            const float* __restrict__ seps,
                                            const float* __restrict__ zT,
                                            float* __restrict__ img_mom,
                                            int opaq) {
    int t = threadIdx.x;
    int grp = t >> 3;
    int m4 = t & 7;
    int n = blockIdx.x * 32 + grp;

    float In = 0.f, Sn = 1.f;
    int g = 0;
    float sd20 = 0.f, sip0 = 0.f, sd21 = 0.f, sip1 = 0.f;

    for (int r = 0; r < REP; ++r) {
        int nb = n + r * opaq;   // 0 offset at runtime
        In = I[nb];
        Sn = SigI[nb];
        g = image_id[nb];
        int rid0 = refl_ids[nb];
        int rid1 = refl_ids[N_OBS_C + nb];
        float4 pp = params[nb];

        float4 ss = *(const float4*)&seps[(size_t)nb * MC_C + m4 * 4];
        float4 z0 = *(const float4*)&zT[(size_t)rid0 * MC_C + m4 * 4];
        float4 z1 = *(const float4*)&zT[(size_t)rid1 * MC_C + m4 * 4];

        float rsig = 1.0f / Sn;
        float mnIr = -In * rsig;

#define MCSTEP(zc0, zc1, sc_)                              \
        {                                                  \
            float sc0 = fmaf(pp.y, sc_, pp.x);             \
            float ip0 = zc0 * sc0;                         \
            float d0 = fmaf(ip0, rsig, mnIr);              \
            sd20 = fmaf(d0, d0, sd20);                     \
            sip0 += ip0;                                   \
            float sc1 = fmaf(pp.w, sc_, pp.z);             \
            float ip1 = zc1 * sc1;                         \
            float d1 = fmaf(ip1, rsig, mnIr);              \
            sd21 = fmaf(d1, d1, sd21);                     \
            sip1 += ip1;                                   \
        }
        MCSTEP(z0.x, z1.x, ss.x)
        MCSTEP(z0.y, z1.y, ss.y)
        MCSTEP(z0.z, z1.z, ss.z)
        MCSTEP(z0.w, z1.w, ss.w)
#undef MCSTEP
    }

    // undo the REP-fold (values were accumulated REP times)
    sd20 *= (1.0f / REP);
    sip0 *= (1.0f / REP);
    sd21 *= (1.0f / REP);
    sip1 *= (1.0f / REP);

#pragma unroll
    for (int o = 4; o > 0; o >>= 1) {
        sd20 += __shfl_xor(sd20, o);
        sd21 += __shfl_xor(sd21, o);
        sip0 += __shfl_xor(sip0, o);
        sip1 += __shfl_xor(sip1, o);
    }

    __shared__ float mom[32][12];
    __shared__ int sg[32];
    __shared__ int sameflag;
    if (m4 == 0) {
        float rsig = 1.0f / Sn;
        float logS32 = 32.f * logf(Sn) + 16.f * LOG2PI_F;
        float y0 = sip0 * (1.0f / 32.0f);
        float y1 = sip1 * (1.0f / 32.0f);
        float w = rsig * rsig;
        mom[grp][0] = -0.5f * sd20 - logS32;
        mom[grp][1] = -0.5f * sd21 - logS32;
        mom[grp][2] = w;
        mom[grp][3] = w * In;
        mom[grp][4] = w * In * In;
        mom[grp][5] = w * y0;
        mom[grp][6] = w * y0 * y0;
        mom[grp][7] = w * In * y0;
        mom[grp][8] = w * y1;
        mom[grp][9] = w * y1 * y1;
        mom[grp][10] = w * In * y1;
        mom[grp][11] = 0.f;
        sg[grp] = g;
    }
    __syncthreads();
    if (t == 0) {
        bool same = true;
        int g0 = sg[0];
#pragma unroll
        for (int s = 1; s < 32; ++s) same = same && (sg[s] == g0);
        sameflag = same;
    }
    __syncthreads();
    int slot = blockIdx.x & (NSLOT - 1);
    if (t < 12) {
        if (sameflag) {
            float a = 0.f;
#pragma unroll
            for (int s = 0; s < 32; ++s) a += mom[s][t];
            atomicAdd(&img_mom[(sg[0] * 12 + t) * NSLOT + slot], a);
        } else {
            for (int s = 0; s < 32; ++s)
                atomicAdd(&img_mom[(sg[s] * 12 + t) * NSLOT + slot], mom[s][t]);
        }
    }
}

// ---- K3: per-image slot-sum + argmax + block-reduced global sums ----
__global__ __launch_bounds__(256) void k_img(const float* __restrict__ img_mom,
                                             double* __restrict__ accs) {
    int g = blockIdx.x * 256 + threadIdx.x;
    double red7[7] = {0, 0, 0, 0, 0, 0, 0};
    if (g < N_IMG_C) {
        float M[12];
#pragma unroll
        for (int j = 0; j < 12; ++j) {
            const float4* p = (const float4*)&img_mom[(g * 12 + j) * NSLOT];
            float4 q0 = p[0], q1 = p[1], q2 = p[2], q3 = p[3];
            M[j] = (q0.x + q0.y + q0.z + q0.w) + (q1.x + q1.y + q1.z + q1.w) +
                   (q2.x + q2.y + q2.z + q2.w) + (q3.x + q3.y + q3.z + q3.w);
        }
        float ll0 = M[0] * (1.0f / 32.0f);
        float ll1 = M[1] * (1.0f / 32.0f);
        bool op1 = (ll1 > ll0);
        red7[0] = (double)fmaxf(ll0, ll1);
        red7[1] = (double)M[2];
        red7[2] = (double)M[3];
        red7[3] = (double)(op1 ? M[8] : M[5]);
        red7[4] = (double)M[4];
        red7[5] = (double)(op1 ? M[9] : M[6]);
        red7[6] = (double)(op1 ? M[10] : M[7]);
    }
#pragma unroll
    for (int k = 0; k < 7; ++k)
        for (int o = 32; o > 0; o >>= 1) red7[k] += __shfl_xor(red7[k], o);
    __shared__ double sred[4][7];
    int lane = threadIdx.x & 63, w = threadIdx.x >> 6;
    if (lane == 0) {
#pragma unroll
        for (int k = 0; k < 7; ++k) sred[w][k] = red7[k];
    }
    __syncthreads();
    if (threadIdx.x < 7) {
        double v = sred[0][threadIdx.x] + sred[1][threadIdx.x] +
                   sred[2][threadIdx.x] + sred[3][threadIdx.x];
        atomicAdd(&accs[1 + threadIdx.x], v);
    }
}

// ---- K5: finalize ----
__global__ void k_final(const double* __restrict__ accs, float* __restrict__ out) {
    double kl = accs[0] / (double)N_REFL_C;
    double elbo = -(accs[1] / (double)N_IMG_C) + 1.0 * kl;
    double W = accs[2], Sx = accs[3], Sy = accs[4];
    double Sxx = accs[5], Syy = accs[6], Sxy = accs[7];
    double z = 1.0 / W;
    double mx = z * Sx, my = z * Sy;
    double cxy = z * Sxy - mx * my;
    double cx = z * Sxx - mx * mx;
    double cy = z * Syy - my * my;
    double cc = cxy / sqrt(cx * cy);
    out[0] = (float)elbo;
    out[1] = (float)cc;
}

extern "C" void kernel_launch(void* const* d_in, const int* in_sizes, int n_in,
                              void* d_out, int out_size, void* d_ws, size_t ws_size,
                              hipStream_t stream) {
    const float* I = (const float*)d_in[0];
    const float* SigI = (const float*)d_in[1];
    const int* image_id = (const int*)d_in[2];
    const float* metadata = (const float*)d_in[3];
    const float* wavelength = (const float*)d_in[4];
    const float* dHKL = (const float*)d_in[5];
    const int* refl_ids = (const int*)d_in[6];
    const float* q_loc = (const float*)d_in[7];
    const float* q_scale_raw = (const float*)d_in[8];
    const float* img_emb = (const float*)d_in[9];
    const float* W1 = (const float*)d_in[10];
    const float* b1 = (const float*)d_in[11];
    const float* W2 = (const float*)d_in[12];
    const float* b2 = (const float*)d_in[13];
    const float* zeps = (const float*)d_in[14];
    const float* seps = (const float*)d_in[15];
    float* out = (float*)d_out;

    char* ws = (char*)d_ws;
    double* accs = (double*)ws;
    float* img_mom = (float*)(ws + 64);
    float* sqv = (float*)(ws + 2097152);
    float* img_pre = (float*)(ws + 4194304);
    float* zT = (float*)(ws + 8388608);
    float4* params = (float4*)(ws + 50331648);

    int opaq = 0;   // opaque-zero passed to instrumented kernels

    k_zero<<<(ZERO_F4 + 255) / 256, 256, 0, stream>>>((float4*)ws);
    k_refl<<<(N_REFL_C + 255) / 256, 256, 0, stream>>>(q_loc, q_scale_raw, zeps,
                                                       sqv, zT, &accs[0]);
    k_imgpre<<<N_IMG_C, 64, 0, stream>>>(img_emb, W1, b1, img_pre);
    k_mlp<<<(N_OBS_C + 511) / 512, 256, 0, stream>>>(I, SigI, image_id, metadata,
                                                     wavelength, dHKL, refl_ids,
                                                     q_loc, W1, W2, b2, sqv,
                                                     img_pre, params, opaq);
    k_mc<<<N_OBS_C / 32, 256, 0, stream>>>(I, SigI, image_id, refl_ids,
                                           params, seps, zT, img_mom, opaq);
    k_img<<<(N_IMG_C + 255) / 256, 256, 0, stream>>>(img_mom, accs);
    k_final<<<1, 1, 0, stream>>>(accs, out);
}

// Round 11
// 271.590 us; speedup vs baseline: 2.2564x; 2.2564x over previous
//
#include <hip/hip_runtime.h>
#include <math.h>

#define N_OBS_C 2000000
#define N_REFL_C 250000
#define N_IMG_C 2000
#define MC_C 32
#define HID 64
#define NSLOT 16
#define LOG2PI_F 1.8378770664093453f

// ---------------- workspace layout (bytes) ----------------
// [0,64)        accs: 8 doubles (kl, llmax, W, Sx, Sy, Sxx, Syy, Sxy)
// [64,1536064)  img_mom [2000][12][NSLOT] float  (zeroed by k_zero)
// [2097152,..)  sq [250000] float
// [4194304,..)  img_pre [2000][64] float
// [8388608,..)  zT [250000][32] float (32MB)
// [50331648,..) params [2000000] float4 (32MB)

typedef float f2 __attribute__((ext_vector_type(2)));

__device__ __forceinline__ void pkfma(f2& d, f2 a, f2 b) {
    // d = a*b + d  (v_pk_fma_f32: one instruction, two fp32 FMAs)
    asm("v_pk_fma_f32 %0, %1, %2, %0" : "+v"(d) : "v"(a), "v"(b));
}
__device__ __forceinline__ f2 pkfma3(f2 a, f2 b, f2 c) {
    // d = a*b + c (fresh destination, c preserved)
    f2 d;
    asm("v_pk_fma_f32 %0, %1, %2, %3" : "=v"(d) : "v"(a), "v"(b), "v"(c));
    return d;
}

__device__ __forceinline__ float softplusf(float x) {
    return (x > 20.f) ? x : log1pf(expf(x));
}

// ---- K0: zero the accumulator region ----
#define ZERO_F4 96004   // (64 + 2000*12*16*4) / 16
__global__ __launch_bounds__(256) void k_zero(float4* __restrict__ p) {
    int i = blockIdx.x * 256 + threadIdx.x;
    if (i < ZERO_F4) p[i] = make_float4(0.f, 0.f, 0.f, 0.f);
}

// ---- K1: per-reflection: sq, KL partial, zT table ----
__global__ __launch_bounds__(256) void k_refl(const float* __restrict__ q_loc,
                                              const float* __restrict__ q_scale_raw,
                                              const float* __restrict__ zeps,
                                              float* __restrict__ sq,
                                              float* __restrict__ zT,
                                              double* __restrict__ kl_sum) {
    int r = blockIdx.x * 256 + threadIdx.x;
    double kl = 0.0;
    if (r < N_REFL_C) {
        float ql = q_loc[r];
        float sp = softplusf(q_scale_raw[r]);
        sq[r] = sp;
        kl = (double)(-logf(sp) + 0.5f * (sp * sp + ql * ql) - 0.5f);
        float z[MC_C];
#pragma unroll
        for (int m = 0; m < MC_C; ++m)
            z[m] = fmaf(sp, zeps[(size_t)m * N_REFL_C + r], ql);
        float4* outp = (float4*)(zT + (size_t)r * MC_C);
#pragma unroll
        for (int q = 0; q < MC_C / 4; ++q)
            outp[q] = make_float4(z[4 * q], z[4 * q + 1], z[4 * q + 2], z[4 * q + 3]);
    }
    for (int o = 32; o > 0; o >>= 1) kl += __shfl_xor(kl, o);
    __shared__ double skl[4];
    int lane = threadIdx.x & 63, w = threadIdx.x >> 6;
    if (lane == 0) skl[w] = kl;
    __syncthreads();
    if (threadIdx.x == 0) atomicAdd(kl_sum, skl[0] + skl[1] + skl[2] + skl[3]);
}

// ---- K1b: per-image precompute ----
__global__ __launch_bounds__(64) void k_imgpre(const float* __restrict__ img_emb,
                                               const float* __restrict__ W1,
                                               const float* __restrict__ b1,
                                               float* __restrict__ img_pre) {
    int g = blockIdx.x;
    int j = threadIdx.x;
    float acc = b1[j];
#pragma unroll
    for (int e = 0; e < 32; ++e)
        acc = fmaf(img_emb[g * 32 + e], W1[(12 + e) * HID + j], acc);
    img_pre[g * HID + j] = acc;
}

// ---- K2a: MLP, 2 obs per thread; weights in LDS; v_pk_fma_f32 core ----
__global__ __launch_bounds__(256) void k_mlp(const float* __restrict__ I,
                                             const float* __restrict__ SigI,
                                             const int* __restrict__ image_id,
                                             const float* __restrict__ metadata,
                                             const float* __restrict__ wavelength,
                                             const float* __restrict__ dHKL,
                                             const int* __restrict__ refl_ids,
                                             const float* __restrict__ q_loc,
                                             const float* __restrict__ W1,
                                             const float* __restrict__ W2,
                                             const float* __restrict__ b2,
                                             const float* __restrict__ sq,
                                             const float* __restrict__ img_pre,
                                             float4* __restrict__ params) {
    __shared__ float sW1[12 * HID];
    __shared__ float sW2a[HID], sW2b[HID];
    for (int t = threadIdx.x; t < 12 * HID; t += 256) sW1[t] = W1[t];
    if (threadIdx.x < HID) {
        sW2a[threadIdx.x] = W2[threadIdx.x * 2 + 0];
        sW2b[threadIdx.x] = W2[threadIdx.x * 2 + 1];
    }
    __syncthreads();

    int n0 = blockIdx.x * 512 + threadIdx.x;
    int n1 = n0 + 256;
    bool a0 = (n0 < N_OBS_C), a1 = (n1 < N_OBS_C);
    int m0 = a0 ? n0 : (N_OBS_C - 1);
    int m1 = a1 ? n1 : (N_OBS_C - 1);

    // features i=2..11 as broadcast pairs
    f2 f0p[10], f1p[10];
    {
        float v;
        v = I[m0];            f0p[0].x = v; f0p[0].y = v;
        v = SigI[m0];         f0p[1].x = v; f0p[1].y = v;
#pragma unroll
        for (int i = 0; i < 6; ++i) {
            v = metadata[(size_t)m0 * 6 + i];
            f0p[2 + i].x = v; f0p[2 + i].y = v;
        }
        v = wavelength[m0];   f0p[8].x = v; f0p[8].y = v;
        float dh = dHKL[m0];
        v = 1.0f / (dh * dh); f0p[9].x = v; f0p[9].y = v;

        v = I[m1];            f1p[0].x = v; f1p[0].y = v;
        v = SigI[m1];         f1p[1].x = v; f1p[1].y = v;
#pragma unroll
        for (int i = 0; i < 6; ++i) {
            v = metadata[(size_t)m1 * 6 + i];
            f1p[2 + i].x = v; f1p[2 + i].y = v;
        }
        v = wavelength[m1];   f1p[8].x = v; f1p[8].y = v;
        dh = dHKL[m1];
        v = 1.0f / (dh * dh); f1p[9].x = v; f1p[9].y = v;
    }

    int g0 = image_id[m0], g1 = image_id[m1];
    int r00 = refl_ids[m0], r01 = refl_ids[N_OBS_C + m0];
    int r10 = refl_ids[m1], r11 = refl_ids[N_OBS_C + m1];
    f2 qa0p, sa0p, qb0p, sb0p, qa1p, sa1p, qb1p, sb1p;
    { float v;
      v = q_loc[r00]; qa0p.x = v; qa0p.y = v;
      v = sq[r00];    sa0p.x = v; sa0p.y = v;
      v = q_loc[r01]; qb0p.x = v; qb0p.y = v;
      v = sq[r01];    sb0p.x = v; sb0p.y = v;
      v = q_loc[r10]; qa1p.x = v; qa1p.y = v;
      v = sq[r10];    sa1p.x = v; sa1p.y = v;
      v = q_loc[r11]; qb1p.x = v; qb1p.y = v;
      v = sq[r11];    sb1p.x = v; sb1p.y = v;
    }
    const float* ip0 = img_pre + (size_t)g0 * HID;
    const float* ip1 = img_pre + (size_t)g1 * HID;

    f2 lA00 = {0.f, 0.f}, lA01 = {0.f, 0.f}, lB00 = {0.f, 0.f}, lB01 = {0.f, 0.f};
    f2 lA10 = {0.f, 0.f}, lA11 = {0.f, 0.f}, lB10 = {0.f, 0.f}, lB11 = {0.f, 0.f};

#pragma unroll 1
    for (int jt = 0; jt < HID; jt += 8) {
        f2 ac0[4], ac1[4];
        {
            float4 pa = *(const float4*)&ip0[jt];
            float4 pb = *(const float4*)&ip0[jt + 4];
            ac0[0].x = pa.x; ac0[0].y = pa.y;
            ac0[1].x = pa.z; ac0[1].y = pa.w;
            ac0[2].x = pb.x; ac0[2].y = pb.y;
            ac0[3].x = pb.z; ac0[3].y = pb.w;
            pa = *(const float4*)&ip1[jt];
            pb = *(const float4*)&ip1[jt + 4];
            ac1[0].x = pa.x; ac1[0].y = pa.y;
            ac1[1].x = pa.z; ac1[1].y = pa.w;
            ac1[2].x = pb.x; ac1[2].y = pb.y;
            ac1[3].x = pb.z; ac1[3].y = pb.w;
        }
#pragma unroll
        for (int i = 0; i < 10; ++i) {
            float4 wa = *(const float4*)&sW1[(i + 2) * HID + jt];
            float4 wb = *(const float4*)&sW1[(i + 2) * HID + jt + 4];
            f2 w0; w0.x = wa.x; w0.y = wa.y;
            f2 w1; w1.x = wa.z; w1.y = wa.w;
            f2 w2; w2.x = wb.x; w2.y = wb.y;
            f2 w3; w3.x = wb.z; w3.y = wb.w;
            pkfma(ac0[0], f0p[i], w0); pkfma(ac1[0], f1p[i], w0);
            pkfma(ac0[1], f0p[i], w1); pkfma(ac1[1], f1p[i], w1);
            pkfma(ac0[2], f0p[i], w2); pkfma(ac1[2], f1p[i], w2);
            pkfma(ac0[3], f0p[i], w3); pkfma(ac1[3], f1p[i], w3);
        }
        f2 w0p[4], w1p[4], vap[4], vbp[4];
        {
            float4 wa = *(const float4*)&sW1[jt];
            float4 wb = *(const float4*)&sW1[jt + 4];
            w0p[0].x = wa.x; w0p[0].y = wa.y;
            w0p[1].x = wa.z; w0p[1].y = wa.w;
            w0p[2].x = wb.x; w0p[2].y = wb.y;
            w0p[3].x = wb.z; w0p[3].y = wb.w;
            wa = *(const float4*)&sW1[HID + jt];
            wb = *(const float4*)&sW1[HID + jt + 4];
            w1p[0].x = wa.x; w1p[0].y = wa.y;
            w1p[1].x = wa.z; w1p[1].y = wa.w;
            w1p[2].x = wb.x; w1p[2].y = wb.y;
            w1p[3].x = wb.z; w1p[3].y = wb.w;
            wa = *(const float4*)&sW2a[jt];
            wb = *(const float4*)&sW2a[jt + 4];
            vap[0].x = wa.x; vap[0].y = wa.y;
            vap[1].x = wa.z; vap[1].y = wa.w;
            vap[2].x = wb.x; vap[2].y = wb.y;
            vap[3].x = wb.z; vap[3].y = wb.w;
            wa = *(const float4*)&sW2b[jt];
            wb = *(const float4*)&sW2b[jt + 4];
            vbp[0].x = wa.x; vbp[0].y = wa.y;
            vbp[1].x = wa.z; vbp[1].y = wa.w;
            vbp[2].x = wb.x; vbp[2].y = wb.y;
            vbp[3].x = wb.z; vbp[3].y = wb.w;
        }
#pragma unroll
        for (int k = 0; k < 4; ++k) {
            f2 h;
            h = pkfma3(sa0p, w1p[k], ac0[k]);
            pkfma(h, qa0p, w0p[k]);
            h.x = fmaxf(h.x, 0.f); h.y = fmaxf(h.y, 0.f);
            pkfma(lA00, h, vap[k]);
            pkfma(lA01, h, vbp[k]);
            h = pkfma3(sb0p, w1p[k], ac0[k]);
            pkfma(h, qb0p, w0p[k]);
            h.x = fmaxf(h.x, 0.f); h.y = fmaxf(h.y, 0.f);
            pkfma(lB00, h, vap[k]);
            pkfma(lB01, h, vbp[k]);
            h = pkfma3(sa1p, w1p[k], ac1[k]);
            pkfma(h, qa1p, w0p[k]);
            h.x = fmaxf(h.x, 0.f); h.y = fmaxf(h.y, 0.f);
            pkfma(lA10, h, vap[k]);
            pkfma(lA11, h, vbp[k]);
            h = pkfma3(sb1p, w1p[k], ac1[k]);
            pkfma(h, qb1p, w0p[k]);
            h.x = fmaxf(h.x, 0.f); h.y = fmaxf(h.y, 0.f);
            pkfma(lB10, h, vap[k]);
            pkfma(lB11, h, vbp[k]);
        }
    }

    float bb0 = b2[0], bb1 = b2[1];
    if (a0) {
        float la0 = bb0 + lA00.x + lA00.y;
        float la1 = bb1 + lA01.x + lA01.y;
        float lb0 = bb0 + lB00.x + lB00.y;
        float lb1 = bb1 + lB01.x + lB01.y;
        params[n0] = make_float4(la0, softplusf(la1), lb0, softplusf(lb1));
    }
    if (a1) {
        float la0 = bb0 + lA10.x + lA10.y;
        float la1 = bb1 + lA11.x + lA11.y;
        float lb0 = bb0 + lB10.x + lB10.y;
        float lb1 = bb1 + lB11.x + lB11.y;
        params[n1] = make_float4(la0, softplusf(la1), lb0, softplusf(lb1));
    }
}

// ---- K2b: MC likelihood + fused per-image moments; 8 lanes/obs ----
__global__ __launch_bounds__(256) void k_mc(const float* __restrict__ I,
                                            const float* __restrict__ SigI,
                                            const int* __restrict__ image_id,
                                            const int* __restrict__ refl_ids,
                                            const float4* __restrict__ params,
                                            const float* __restrict__ seps,
                                            const float* __restrict__ zT,
                                            float* __restrict__ img_mom) {
    int t = threadIdx.x;
    int grp = t >> 3;
    int m4 = t & 7;
    int n = blockIdx.x * 32 + grp;

    float In = I[n];
    float Sn = SigI[n];
    int g = image_id[n];
    int rid0 = refl_ids[n];
    int rid1 = refl_ids[N_OBS_C + n];
    float4 pp = params[n];

    float4 ss = *(const float4*)&seps[(size_t)n * MC_C + m4 * 4];
    float4 z0 = *(const float4*)&zT[(size_t)rid0 * MC_C + m4 * 4];
    float4 z1 = *(const float4*)&zT[(size_t)rid1 * MC_C + m4 * 4];

    float rsig = 1.0f / Sn;
    float mnIr = -In * rsig;

    float sd20 = 0.f, sip0 = 0.f, sd21 = 0.f, sip1 = 0.f;
#define MCSTEP(zc0, zc1, sc_)                              \
    {                                                      \
        float sc0 = fmaf(pp.y, sc_, pp.x);                 \
        float ip0 = zc0 * sc0;                             \
        float d0 = fmaf(ip0, rsig, mnIr);                  \
        sd20 = fmaf(d0, d0, sd20);                         \
        sip0 += ip0;                                       \
        float sc1 = fmaf(pp.w, sc_, pp.z);                 \
        float ip1 = zc1 * sc1;                             \
        float d1 = fmaf(ip1, rsig, mnIr);                  \
        sd21 = fmaf(d1, d1, sd21);                         \
        sip1 += ip1;                                       \
    }
    MCSTEP(z0.x, z1.x, ss.x)
    MCSTEP(z0.y, z1.y, ss.y)
    MCSTEP(z0.z, z1.z, ss.z)
    MCSTEP(z0.w, z1.w, ss.w)
#undef MCSTEP

#pragma unroll
    for (int o = 4; o > 0; o >>= 1) {
        sd20 += __shfl_xor(sd20, o);
        sd21 += __shfl_xor(sd21, o);
        sip0 += __shfl_xor(sip0, o);
        sip1 += __shfl_xor(sip1, o);
    }

    __shared__ float mom[32][12];
    __shared__ int sg[32];
    __shared__ int sameflag;
    if (m4 == 0) {
        float logS32 = 32.f * logf(Sn) + 16.f * LOG2PI_F;
        float y0 = sip0 * (1.0f / 32.0f);
        float y1 = sip1 * (1.0f / 32.0f);
        float w = rsig * rsig;
        mom[grp][0] = -0.5f * sd20 - logS32;
        mom[grp][1] = -0.5f * sd21 - logS32;
        mom[grp][2] = w;
        mom[grp][3] = w * In;
        mom[grp][4] = w * In * In;
        mom[grp][5] = w * y0;
        mom[grp][6] = w * y0 * y0;
        mom[grp][7] = w * In * y0;
        mom[grp][8] = w * y1;
        mom[grp][9] = w * y1 * y1;
        mom[grp][10] = w * In * y1;
        mom[grp][11] = 0.f;
        sg[grp] = g;
    }
    __syncthreads();
    if (t == 0) {
        bool same = true;
        int g0 = sg[0];
#pragma unroll
        for (int s = 1; s < 32; ++s) same = same && (sg[s] == g0);
        sameflag = same;
    }
    __syncthreads();
    int slot = blockIdx.x & (NSLOT - 1);
    if (t < 12) {
        if (sameflag) {
            float a = 0.f;
#pragma unroll
            for (int s = 0; s < 32; ++s) a += mom[s][t];
            atomicAdd(&img_mom[(sg[0] * 12 + t) * NSLOT + slot], a);
        } else {
            for (int s = 0; s < 32; ++s)
                atomicAdd(&img_mom[(sg[s] * 12 + t) * NSLOT + slot], mom[s][t]);
        }
    }
}

// ---- K3: per-image slot-sum + argmax + block-reduced global sums ----
__global__ __launch_bounds__(256) void k_img(const float* __restrict__ img_mom,
                                             double* __restrict__ accs) {
    int g = blockIdx.x * 256 + threadIdx.x;
    double red7[7] = {0, 0, 0, 0, 0, 0, 0};
    if (g < N_IMG_C) {
        float M[12];
#pragma unroll
        for (int j = 0; j < 12; ++j) {
            const float4* p = (const float4*)&img_mom[(g * 12 + j) * NSLOT];
            float4 q0 = p[0], q1 = p[1], q2 = p[2], q3 = p[3];
            M[j] = (q0.x + q0.y + q0.z + q0.w) + (q1.x + q1.y + q1.z + q1.w) +
                   (q2.x + q2.y + q2.z + q2.w) + (q3.x + q3.y + q3.z + q3.w);
        }
        float ll0 = M[0] * (1.0f / 32.0f);
        float ll1 = M[1] * (1.0f / 32.0f);
        bool op1 = (ll1 > ll0);
        red7[0] = (double)fmaxf(ll0, ll1);
        red7[1] = (double)M[2];
        red7[2] = (double)M[3];
        red7[3] = (double)(op1 ? M[8] : M[5]);
        red7[4] = (double)M[4];
        red7[5] = (double)(op1 ? M[9] : M[6]);
        red7[6] = (double)(op1 ? M[10] : M[7]);
    }
#pragma unroll
    for (int k = 0; k < 7; ++k)
        for (int o = 32; o > 0; o >>= 1) red7[k] += __shfl_xor(red7[k], o);
    __shared__ double sred[4][7];
    int lane = threadIdx.x & 63, w = threadIdx.x >> 6;
    if (lane == 0) {
#pragma unroll
        for (int k = 0; k < 7; ++k) sred[w][k] = red7[k];
    }
    __syncthreads();
    if (threadIdx.x < 7) {
        double v = sred[0][threadIdx.x] + sred[1][threadIdx.x] +
                   sred[2][threadIdx.x] + sred[3][threadIdx.x];
        atomicAdd(&accs[1 + threadIdx.x], v);
    }
}

// ---- K5: finalize ----
__global__ void k_final(const double* __restrict__ accs, float* __restrict__ out) {
    double kl = accs[0] / (double)N_REFL_C;
    double elbo = -(accs[1] / (double)N_IMG_C) + 1.0 * kl;
    double W = accs[2], Sx = accs[3], Sy = accs[4];
    double Sxx = accs[5], Syy = accs[6], Sxy = accs[7];
    double z = 1.0 / W;
    double mx = z * Sx, my = z * Sy;
    double cxy = z * Sxy - mx * my;
    double cx = z * Sxx - mx * mx;
    double cy = z * Syy - my * my;
    double cc = cxy / sqrt(cx * cy);
    out[0] = (float)elbo;
    out[1] = (float)cc;
}

extern "C" void kernel_launch(void* const* d_in, const int* in_sizes, int n_in,
                              void* d_out, int out_size, void* d_ws, size_t ws_size,
                              hipStream_t stream) {
    const float* I = (const float*)d_in[0];
    const float* SigI = (const float*)d_in[1];
    const int* image_id = (const int*)d_in[2];
    const float* metadata = (const float*)d_in[3];
    const float* wavelength = (const float*)d_in[4];
    const float* dHKL = (const float*)d_in[5];
    const int* refl_ids = (const int*)d_in[6];
    const float* q_loc = (const float*)d_in[7];
    const float* q_scale_raw = (const float*)d_in[8];
    const float* img_emb = (const float*)d_in[9];
    const float* W1 = (const float*)d_in[10];
    const float* b1 = (const float*)d_in[11];
    const float* W2 = (const float*)d_in[12];
    const float* b2 = (const float*)d_in[13];
    const float* zeps = (const float*)d_in[14];
    const float* seps = (const float*)d_in[15];
    float* out = (float*)d_out;

    char* ws = (char*)d_ws;
    double* accs = (double*)ws;
    float* img_mom = (float*)(ws + 64);
    float* sqv = (float*)(ws + 2097152);
    float* img_pre = (float*)(ws + 4194304);
    float* zT = (float*)(ws + 8388608);
    float4* params = (float4*)(ws + 50331648);

    k_zero<<<(ZERO_F4 + 255) / 256, 256, 0, stream>>>((float4*)ws);
    k_refl<<<(N_REFL_C + 255) / 256, 256, 0, stream>>>(q_loc, q_scale_raw, zeps,
                                                       sqv, zT, &accs[0]);
    k_imgpre<<<N_IMG_C, 64, 0, stream>>>(img_emb, W1, b1, img_pre);
    k_mlp<<<(N_OBS_C + 511) / 512, 256, 0, stream>>>(I, SigI, image_id, metadata,
                                                     wavelength, dHKL, refl_ids,
                                                     q_loc, W1, W2, b2, sqv,
                                                     img_pre, params);
    k_mc<<<N_OBS_C / 32, 256, 0, stream>>>(I, SigI, image_id, refl_ids,
                                           params, seps, zT, img_mom);
    k_img<<<(N_IMG_C + 255) / 256, 256, 0, stream>>>(img_mom, accs);
    k_final<<<1, 1, 0, stream>>>(accs, out);
}